// Round 16
// baseline (121.121 us; speedup 1.0000x reference)
//
#include <hip/hip_runtime.h>
#include <hip/hip_bf16.h>

#define N_NODES 100000
#define E_EDGES 1600000
#define DIN 256
#define C_OUT 64
#define NID_CNT 10000
#define NEG 0.2f
#define NBUCK 391        // ceil(N_NODES/256) coarse buckets (dst >> 8)
#define CAP 4608         // fixed edges-capacity per bucket
#define GEMM_BLOCKS 782  // 128 rows/block
#define BIN_BLOCKS 121
#define BIN_EPB 13224    // ceil(E_EDGES/121)
#define BIN_ITERS 26     // ceil(13224/512)

typedef short bf16x8 __attribute__((ext_vector_type(8)));
typedef float f32x4  __attribute__((ext_vector_type(4)));

__device__ __forceinline__ float lrelu(float x) { return x > 0.f ? x : NEG * x; }
__device__ __forceinline__ unsigned short f2bs(float f) {
    __hip_bfloat16 b = __float2bfloat16(f);
    return *reinterpret_cast<unsigned short*>(&b);
}
__device__ __forceinline__ uint2 pack4(float4 v) {
    uint2 r;
    r.x = ((unsigned)f2bs(v.y) << 16) | f2bs(v.x);
    r.y = ((unsigned)f2bs(v.w) << 16) | f2bs(v.z);
    return r;
}
__device__ __forceinline__ float2 unpk2(unsigned u) {
    return make_float2(__uint_as_float(u << 16), __uint_as_float(u & 0xffff0000u));
}

// ---------------- zero/init scratch ----------------
__global__ __launch_bounds__(256) void k_zero(float* __restrict__ cnt,
                                              int* __restrict__ bkcur) {
    const int t = blockIdx.x * 256 + threadIdx.x;
    if (t < N_NODES) cnt[t] = 0.f;
    if (t < NBUCK) bkcur[t] = t * CAP;
}

// ---------------- prep: W/Wid cvt+transpose | id multiplicity ----------------
__global__ __launch_bounds__(256) void k_prep(const float* __restrict__ W,
                                              const float* __restrict__ Wid,
                                              unsigned short* __restrict__ WtG,
                                              unsigned short* __restrict__ WidtG,
                                              const int* __restrict__ nid,
                                              float* __restrict__ cnt) {
    const int b = blockIdx.x;
    const int tid = threadIdx.x;
    if (b < 128) {
        const int t = b * 256 + tid;
        const int mat = t >> 14;
        const int r = t & 16383;
        const int k = r >> 6, c = r & 63;
        if (mat == 0) WtG[c * DIN + k] = f2bs(W[(long)k * C_OUT + c]);
        else          WidtG[c * DIN + k] = f2bs(Wid[(long)k * C_OUT + c]);
    } else {
        const int t = (b - 128) * 256 + tid;
        if (t < NID_CNT) atomicAdd(&cnt[nid[t]], 1.0f);
    }
}

// ---------------- mega: gemm blocks (0..781) || bin blocks (782..902) ----------------
// gemm: 512 thr = 8 waves x 16 rows = 128 rows/block. x staged via CONTIGUOUS
// 512B-run loads -> bf16 pack -> swizzled LDS tile, double-buffered K-halves
// (half1 loads in flight under half0 MFMAs). Wt/Wid in LDS as before.
// bin: register-staged two-phase scatter (u32-packed entries).
__global__ __launch_bounds__(512, 2) void k_mega(const float* __restrict__ x,
                                                 const unsigned short* __restrict__ WtG,
                                                 const unsigned short* __restrict__ WidtG,
                                                 const float* __restrict__ cnt,
                                                 const float* __restrict__ att,
                                                 __hip_bfloat16* __restrict__ hb,
                                                 float* __restrict__ ad,
                                                 float* __restrict__ as,
                                                 const int* __restrict__ ei,
                                                 int* __restrict__ bkcur,
                                                 unsigned* __restrict__ binned) {
    __shared__ __align__(16) char smem[131584];  // wlds 64KB | xh 2x32KB | cnt_lds 512B
    const int blk = blockIdx.x;
    const int tid = threadIdx.x;

    if (blk < GEMM_BLOCKS) {
        char* wlds = smem;
        char* xh   = smem + 65536;
        float* cnt_lds = (float*)(smem + 131072);
        const int w = tid >> 6, l = tid & 63;
        const int g = l >> 4, cl = l & 15;
        const int l31 = l & 31, rh = l >> 5;
        const int r0 = blk * 128;

        // x half0 loads: wave-load = rows (w*16+2j+rh), cols l31*4 (512B runs)
        float4 xv[8];
        #pragma unroll
        for (int j = 0; j < 8; ++j) {
            int row = w * 16 + j * 2 + rh;
            int grow = min(r0 + row, N_NODES - 1);
            xv[j] = *(const float4*)(x + (long)grow * DIN + l31 * 4);
        }
        // W stage (swizzled, as before)
        #pragma unroll
        for (int i = 0; i < 4; ++i) {
            int f = tid + i * 512;
            int c = f >> 5, s = f & 31;
            int byte = c * 512 + ((s ^ (c & 7)) << 4);
            *(bf16x8*)(wlds + byte)         = *(const bf16x8*)(WtG + (long)c * DIN + s * 8);
            *(bf16x8*)(wlds + 32768 + byte) = *(const bf16x8*)(WidtG + (long)c * DIN + s * 8);
        }
        if (tid < 128) cnt_lds[tid] = (r0 + tid < N_NODES) ? cnt[r0 + tid] : 0.f;
        // pack+write half0: row stride 256B, 16B-chunk XOR swizzle by row&15
        #pragma unroll
        for (int j = 0; j < 8; ++j) {
            int row = w * 16 + j * 2 + rh;
            int byte = row * 256 + (((l31 >> 1) ^ (row & 15)) << 4) + (l31 & 1) * 8;
            *(uint2*)(xh + byte) = pack4(xv[j]);
        }
        // issue half1 loads (in flight across barrier + compute0)
        #pragma unroll
        for (int j = 0; j < 8; ++j) {
            int row = w * 16 + j * 2 + rh;
            int grow = min(r0 + row, N_NODES - 1);
            xv[j] = *(const float4*)(x + (long)grow * DIN + 128 + l31 * 4);
        }
        __syncthreads();

        f32x4 acc1[4] = {};
        f32x4 acc2[4] = {};
        const int arow = w * 16 + cl;
        const int axor = (arow & 15);

        // compute half0: kt = 0..3
        #pragma unroll
        for (int kt = 0; kt < 4; ++kt) {
            bf16x8 a0 = *(const bf16x8*)(xh + arow * 256 + (((kt * 4 + g) ^ axor) << 4));
            #pragma unroll
            for (int ct = 0; ct < 4; ++ct) {
                int c = ct * 16 + cl;
                int wbyte = c * 512 + (((kt * 4 + g) ^ (c & 7)) << 4);
                bf16x8 bw = *(const bf16x8*)(wlds + wbyte);
                bf16x8 bi = *(const bf16x8*)(wlds + 32768 + wbyte);
                acc1[ct] = __builtin_amdgcn_mfma_f32_16x16x32_bf16(a0, bw, acc1[ct], 0, 0, 0);
                acc2[ct] = __builtin_amdgcn_mfma_f32_16x16x32_bf16(a0, bi, acc2[ct], 0, 0, 0);
            }
        }
        // pack+write half1
        #pragma unroll
        for (int j = 0; j < 8; ++j) {
            int row = w * 16 + j * 2 + rh;
            int byte = 32768 + row * 256 + (((l31 >> 1) ^ (row & 15)) << 4) + (l31 & 1) * 8;
            *(uint2*)(xh + byte) = pack4(xv[j]);
        }
        __syncthreads();
        // compute half1: kt = 4..7
        #pragma unroll
        for (int kt = 4; kt < 8; ++kt) {
            int kt2 = kt - 4;
            bf16x8 a0 = *(const bf16x8*)(xh + 32768 + arow * 256 + (((kt2 * 4 + g) ^ axor) << 4));
            #pragma unroll
            for (int ct = 0; ct < 4; ++ct) {
                int c = ct * 16 + cl;
                int wbyte = c * 512 + (((kt * 4 + g) ^ (c & 7)) << 4);
                bf16x8 bw = *(const bf16x8*)(wlds + wbyte);
                bf16x8 bi = *(const bf16x8*)(wlds + 32768 + wbyte);
                acc1[ct] = __builtin_amdgcn_mfma_f32_16x16x32_bf16(a0, bw, acc1[ct], 0, 0, 0);
                acc2[ct] = __builtin_amdgcn_mfma_f32_16x16x32_bf16(a0, bi, acc2[ct], 0, 0, 0);
            }
        }
        __syncthreads();   // wlds reads done; reuse as hb tile

        // epilogue
        float attv1[4], attv2[4];
        #pragma unroll
        for (int ct = 0; ct < 4; ++ct) {
            attv1[ct] = att[ct * 16 + cl];
            attv2[ct] = att[C_OUT + ct * 16 + cl];
        }
        unsigned short* hbt = (unsigned short*)wlds;   // [128 rows][stride 72] (144B)
        #pragma unroll
        for (int reg = 0; reg < 4; ++reg) {
            const int rbl = w * 16 + g * 4 + reg;      // 0..127
            const float cv = cnt_lds[rbl];
            float pd = 0.f, ps = 0.f;
            #pragma unroll
            for (int ct = 0; ct < 4; ++ct) {
                float hv = acc1[ct][reg] + cv * acc2[ct][reg];
                pd += hv * attv1[ct];
                ps += hv * attv2[ct];
                hbt[rbl * 72 + ct * 16 + cl] = f2bs(hv);
            }
            #pragma unroll
            for (int o = 1; o < 16; o <<= 1) {
                pd += __shfl_xor(pd, o, 64);
                ps += __shfl_xor(ps, o, 64);
            }
            if (cl == 0) {
                int grow = r0 + rbl;
                if (grow < N_NODES) { ad[grow] = pd; as[grow] = ps; }
            }
        }
        __syncthreads();
        #pragma unroll
        for (int i = 0; i < 2; ++i) {
            int f = tid + i * 512;        // 1024 units of 16B
            int row = f >> 3, s = f & 7;
            int grow = r0 + row;
            if (grow < N_NODES) {
                bf16x8 v = *(const bf16x8*)(wlds + row * 144 + s * 16);
                *(bf16x8*)((unsigned short*)hb + (long)grow * C_OUT + s * 8) = v;
            }
        }
    } else {
        // ---- bin role: register-staged two-phase scatter into bucket regions ----
        int* cnt_s = (int*)smem;
        int* base  = cnt_s + NBUCK;
        int* lcur  = base + NBUCK;
        const int b2 = blk - GEMM_BLOCKS;
        const int e0 = b2 * BIN_EPB;
        const int e1 = min(e0 + BIN_EPB, E_EDGES);
        for (int i = tid; i < NBUCK; i += 512) cnt_s[i] = 0;
        __syncthreads();
        int se[BIN_ITERS], de[BIN_ITERS];
        #pragma unroll
        for (int j = 0; j < BIN_ITERS; ++j) {
            int e = e0 + j * 512 + tid;
            if (e < e1) {
                se[j] = ei[e];
                de[j] = ei[E_EDGES + e];
                atomicAdd(&cnt_s[de[j] >> 8], 1);
            } else de[j] = -1;
        }
        __syncthreads();
        for (int i = tid; i < NBUCK; i += 512) {
            base[i] = cnt_s[i] ? atomicAdd(&bkcur[i], cnt_s[i]) : 0;
            lcur[i] = 0;
        }
        __syncthreads();
        #pragma unroll
        for (int j = 0; j < BIN_ITERS; ++j) {
            if (de[j] >= 0) {
                int bb = de[j] >> 8;
                int r = atomicAdd(&lcur[bb], 1);
                binned[base[bb] + r] = ((unsigned)se[j] << 8) | (unsigned)(de[j] & 255);
            }
        }
    }
}

// ---------------- place: one block per bucket -> fixed-capacity csr + cur ----------------
__global__ __launch_bounds__(256) void k_place(const unsigned* __restrict__ binned,
                                               const int* __restrict__ bkcur,
                                               int* __restrict__ csr,
                                               int* __restrict__ cur) {
    __shared__ int ncnt[256];
    __shared__ int tmp[256];
    __shared__ int ncur[256];
    const int tid = threadIdx.x;
    const int b = blockIdx.x;
    const int lo = b * CAP;
    const int n = bkcur[b] - lo;
    const int node0 = b << 8;
    ncnt[tid] = 0;
    __syncthreads();
    for (int e = tid; e < n; e += 256)
        atomicAdd(&ncnt[binned[lo + e] & 255u], 1);
    __syncthreads();
    const int v = ncnt[tid];
    tmp[tid] = v;
    __syncthreads();
    for (int o = 1; o < 256; o <<= 1) {
        int t = (tid >= o) ? tmp[tid - o] : 0;
        __syncthreads();
        tmp[tid] += t;
        __syncthreads();
    }
    const int incl = tmp[tid];
    if (node0 + tid < N_NODES) cur[node0 + tid] = lo + incl;  // global inclusive end
    ncur[tid] = incl - v;
    __syncthreads();
    for (int e = tid; e < n; e += 256) {
        unsigned p = binned[lo + e];
        int r = atomicAdd(&ncur[p & 255u], 1);
        csr[lo + r] = (int)(p >> 8);
    }
}

// ---------------- gather: 2 nodes/wave (32-lane groups), bf16x2 channels ----------------
__global__ __launch_bounds__(256) void k_gather(const int* __restrict__ cur,
                                                const int* __restrict__ csr,
                                                const unsigned* __restrict__ hb2,
                                                const float* __restrict__ ad,
                                                const float* __restrict__ as,
                                                float* __restrict__ out) {
    const int lane = threadIdx.x & 63;
    const int lg = lane & 31;
    const int gb = lane & 32;
    const int i = blockIdx.x * 8 + ((threadIdx.x >> 6) << 1) + (lane >> 5);
    if (i >= N_NODES) return;
    const int end   = cur[i];
    const int start = (i & 255) ? cur[i - 1] : (i >> 8) * CAP;
    const int deg   = end - start;
    const float adi = ad[i];
    const float asi = as[i];
    float2 acc;
    float den;
    if (deg <= 32) {
        int s = 0; float a = -1e30f;
        if (lg < deg) { s = csr[start + lg]; a = as[s]; }
        float mx = fmaxf(a, asi);
        #pragma unroll
        for (int o = 16; o > 0; o >>= 1) mx = fmaxf(mx, __shfl_xor(mx, o, 64));
        const float m = lrelu(adi + mx);
        float w = (lg < deg) ? __expf(lrelu(adi + a) - m) : 0.f;
        const float wself = __expf(lrelu(adi + asi) - m);
        float wsum = w;
        #pragma unroll
        for (int o = 16; o > 0; o >>= 1) wsum += __shfl_xor(wsum, o, 64);
        den = wself + wsum;
        float2 hv = unpk2(hb2[(long)i * 32 + lg]);
        acc = make_float2(wself * hv.x, wself * hv.y);
        int j = 0;
        for (; j + 4 <= deg; j += 4) {
            int   s0 = __shfl(s, gb + j, 64),     s1 = __shfl(s, gb + j + 1, 64),
                  s2 = __shfl(s, gb + j + 2, 64), s3 = __shfl(s, gb + j + 3, 64);
            float w0 = __shfl(w, gb + j, 64),     w1 = __shfl(w, gb + j + 1, 64),
                  w2 = __shfl(w, gb + j + 2, 64), w3 = __shfl(w, gb + j + 3, 64);
            float2 h0 = unpk2(hb2[(long)s0 * 32 + lg]);
            float2 h1 = unpk2(hb2[(long)s1 * 32 + lg]);
            float2 h2 = unpk2(hb2[(long)s2 * 32 + lg]);
            float2 h3 = unpk2(hb2[(long)s3 * 32 + lg]);
            acc.x += w0 * h0.x; acc.y += w0 * h0.y;
            acc.x += w1 * h1.x; acc.y += w1 * h1.y;
            acc.x += w2 * h2.x; acc.y += w2 * h2.y;
            acc.x += w3 * h3.x; acc.y += w3 * h3.y;
        }
        for (; j < deg; ++j) {
            int   sj = __shfl(s, gb + j, 64);
            float wj = __shfl(w, gb + j, 64);
            float2 hj = unpk2(hb2[(long)sj * 32 + lg]);
            acc.x += wj * hj.x; acc.y += wj * hj.y;
        }
    } else {
        float mx = asi;
        for (int b = 0; b < deg; b += 32) {
            int idx = b + lg;
            if (idx < deg) mx = fmaxf(mx, as[csr[start + idx]]);
        }
        #pragma unroll
        for (int o = 16; o > 0; o >>= 1) mx = fmaxf(mx, __shfl_xor(mx, o, 64));
        const float m = lrelu(adi + mx);
        const float wself = __expf(lrelu(adi + asi) - m);
        float2 hv = unpk2(hb2[(long)i * 32 + lg]);
        acc = make_float2(wself * hv.x, wself * hv.y);
        den = wself;
        for (int b = 0; b < deg; b += 32) {
            int idx = b + lg;
            int s = 0; float w = 0.f;
            if (idx < deg) {
                s = csr[start + idx];
                w = __expf(lrelu(adi + as[s]) - m);
            }
            const int cnt2 = min(32, deg - b);
            for (int j = 0; j < cnt2; ++j) {
                int   sj = __shfl(s, gb + j, 64);
                float wj = __shfl(w, gb + j, 64);
                float2 hj = unpk2(hb2[(long)sj * 32 + lg]);
                acc.x += wj * hj.x; acc.y += wj * hj.y;
            }
            float wsum = w;
            #pragma unroll
            for (int o = 16; o > 0; o >>= 1) wsum += __shfl_xor(wsum, o, 64);
            den += wsum;
        }
    }
    const float r = 1.f / (den + 1e-16f);
    *(float2*)(out + (long)i * C_OUT + lg * 2) = make_float2(acc.x * r, acc.y * r);
}

extern "C" void kernel_launch(void* const* d_in, const int* in_sizes, int n_in,
                              void* d_out, int out_size, void* d_ws, size_t ws_size,
                              hipStream_t stream) {
    const float* x   = (const float*)d_in[0];
    const int*   ei  = (const int*)d_in[1];
    const int*   nid = (const int*)d_in[2];
    const float* W   = (const float*)d_in[3];
    const float* Wid = (const float*)d_in[4];
    const float* att = (const float*)d_in[5];
    float* out = (float*)d_out;

    char* ws = (char*)d_ws;
    __hip_bfloat16* hb = (__hip_bfloat16*)(ws);            // 12,800,000 B
    float* ad    = (float*)(ws + 12800000);                //    400,000 B
    float* as    = (float*)(ws + 13200000);                //    400,000 B
    float* cnt   = (float*)(ws + 13600000);                //    400,000 B
    int*   cur   = (int*)  (ws + 14000000);                //    400,000 B
    unsigned* binned = (unsigned*)(ws + 14400000);         //  7,206,912 B (NBUCK*CAP*4)
    int*   csr   = (int*)  (ws + 21700000);                //  7,206,912 B (NBUCK*CAP*4)
    unsigned short* WtG  = (unsigned short*)(ws + 29000000);  // 32,768 B
    unsigned short* WidG = (unsigned short*)(ws + 29032768);  // 32,768 B
    int*   bkcur = (int*)  (ws + 29065536);                //      1,564 B

    // init: cnt=0, bkcur[b]=b*CAP
    k_zero<<<393, 256, 0, stream>>>(cnt, bkcur);
    // prep: weight cvt+transpose | id multiplicity
    k_prep<<<168, 256, 0, stream>>>(W, Wid, WtG, WidG, nid, cnt);
    // mega: gemm (782 blocks, contiguous-staged x) || edge binning (121 blocks)
    k_mega<<<GEMM_BLOCKS + BIN_BLOCKS, 512, 0, stream>>>(x, WtG, WidG, cnt, att,
                                                         hb, ad, as, ei, bkcur, binned);
    // place: bucket-local hist/scan -> fixed-capacity csr + cur
    k_place<<<NBUCK, 256, 0, stream>>>(binned, bkcur, csr, cur);
    // gather: full-TLP v2
    k_gather<<<12500, 256, 0, stream>>>(cur, csr, (const unsigned*)hb, ad, as, out);
}